// Round 1
// baseline (419.022 us; speedup 1.0000x reference)
//
#include <hip/hip_runtime.h>
#include <hip/hip_bf16.h>

#define EPS 1e-4f
#define ITERS 16
#define INVN (1.0f/512.0f)

// ws layout (bytes):
// det:0  invES:256  u:4096(16KB)  v:20480(16KB)  bsum:36864(32KB)  a:69632(512KB)  bv:593920(512KB)

// Detect mask element size: bool(1B) vs int32 vs int64, by inspecting first 4096 bytes.
__global__ void detect_mask_kernel(const unsigned char* __restrict__ m, int* __restrict__ det) {
  __shared__ unsigned s[2];
  int t = threadIdx.x;
  if (t == 0) { s[0] = 0u; s[1] = 0u; }
  __syncthreads();
  unsigned orb = 0, orc = 0;
  for (int i = t * 16; i < t * 16 + 16; ++i) {
    unsigned val = m[i];
    if (i & 3) orb |= val;            // nonzero only if 1-byte elements
    if ((i & 7) == 4) orc |= val;     // nonzero only if 4-byte elements
  }
  atomicOr(&s[0], orb);
  atomicOr(&s[1], orc);
  __syncthreads();
  if (t == 0) det[0] = s[0] ? 0 : (s[1] ? 1 : 2);  // 0=bool,1=int32,2=int64
}

// a = (emb_out + pos) @ W_out + b_out ; b = where(mask,pad,emb_in) @ W_in + b_in
// block 256 = 32 m-lanes x 8 nodes; grid 512
__global__ void embed_gemm_kernel(const float* __restrict__ emb_in, const void* __restrict__ maskp,
                                  const float* __restrict__ emb_out, const float* __restrict__ pad,
                                  const float* __restrict__ pos, const float* __restrict__ Win,
                                  const float* __restrict__ bin, const float* __restrict__ Wout,
                                  const float* __restrict__ bout, const int* __restrict__ det,
                                  float* __restrict__ aout, float* __restrict__ bvout) {
  int t = threadIdx.x;
  int m = t & 31, nl = t >> 5;
  int g = blockIdx.x * 8 + nl;        // global node 0..4095
  int n = g & 511;
  int dv = det[0];
  int mv;
  if (dv == 0)       mv = ((const unsigned char*)maskp)[g];
  else if (dv == 1)  mv = ((const int*)maskp)[g];
  else               mv = (int)((const long long*)maskp)[g];
  float aa = bout[m], bb = bin[m];
  const float* eo = emb_out + (size_t)g * 256;
  const float* ei = emb_in + (size_t)g * 256;
  const float* pp = pos + (size_t)n * 256;
  for (int d = 0; d < 256; ++d) {
    float x = eo[d] + pp[d];
    float y = mv ? pad[d] : ei[d];
    aa = fmaf(x, Wout[d * 32 + m], aa);
    bb = fmaf(y, Win[d * 32 + m], bb);
  }
  aout[g * 32 + m] = aa;
  bvout[g * 32 + m] = bb;
}

// C[b,i,j] = sum_m |a[b,i,m]-bv[b,j,m]|  (16x16 tile per block) + per-block partial sums
__global__ void cost_kernel(const float* __restrict__ a, const float* __restrict__ bv,
                            float* __restrict__ C, float* __restrict__ bsum) {
  __shared__ float as_[16][33], bs_[16][33];
  __shared__ float rs[256];
  int bt = blockIdx.x;
  int batch = bt >> 10, tile = bt & 1023;
  int it = tile >> 5, jt = tile & 31;
  int t = threadIdx.x;
  for (int k = t; k < 512; k += 256) {
    int r = k >> 5, m = k & 31;
    as_[r][m] = a[(batch * 512 + it * 16 + r) * 32 + m];
    bs_[r][m] = bv[(batch * 512 + jt * 16 + r) * 32 + m];
  }
  __syncthreads();
  int ty = t >> 4, tx = t & 15;
  float s = 0.f;
#pragma unroll
  for (int m = 0; m < 32; ++m) s += fabsf(as_[ty][m] - bs_[tx][m]);
  C[(size_t)(batch * 512 + it * 16 + ty) * 512 + jt * 16 + tx] = s;
  rs[t] = s;
  __syncthreads();
  for (int off = 128; off; off >>= 1) {
    if (t < off) rs[t] += rs[t + off];
    __syncthreads();
  }
  if (t == 0) bsum[bt] = rs[0];
}

// Sum 1024 tile-partials per batch -> invES[b] = -1/(EPS * S_b)
__global__ void norm_kernel(const float* __restrict__ bsum, float* __restrict__ invES) {
  __shared__ float rs[256];
  int b = blockIdx.x, t = threadIdx.x;
  float s = 0.f;
  for (int k = t; k < 1024; k += 256) s += bsum[b * 1024 + k];
  rs[t] = s;
  __syncthreads();
  for (int off = 128; off; off >>= 1) {
    if (t < off) rs[t] += rs[t + off];
    __syncthreads();
  }
  if (t == 0) invES[b] = -1.0f / (EPS * rs[0]);
}

// K = exp(C * invES[b]) in place (float4; 65536 f4 per batch)
__global__ void expk_kernel(float* __restrict__ C, const float* __restrict__ invES) {
  int i = blockIdx.x * 256 + threadIdx.x;   // f4 index, 524288 total
  float s = invES[i >> 16];
  float4 c = ((float4*)C)[i];
  c.x = __expf(c.x * s); c.y = __expf(c.y * s);
  c.z = __expf(c.z * s); c.w = __expf(c.w * s);
  ((float4*)C)[i] = c;
}

// u[b,i] = (1/n) / sum_j K[b,i,j]*v[b,j]   (one wave per row)
__global__ void row_kernel(const float* __restrict__ K, const float* __restrict__ v,
                           float* __restrict__ u, int useV) {
  int t = threadIdx.x;
  int w = blockIdx.x * 4 + (t >> 6);
  int b = w >> 9, i = w & 511, lane = t & 63;
  const float* Kr = K + (size_t)(b * 512 + i) * 512;
  const float* vb = v + b * 512;
  float acc = 0.f;
  if (useV) {
    for (int j = lane; j < 512; j += 64) acc += Kr[j] * vb[j];
  } else {
    for (int j = lane; j < 512; j += 64) acc += Kr[j];
  }
#pragma unroll
  for (int off = 32; off; off >>= 1) acc += __shfl_down(acc, off);
  if (lane == 0) u[b * 512 + i] = INVN / acc;
}

// v[b,j] = (1/n) / sum_i K[b,i,j]*u[b,i]   (block = 64 columns of one batch, 4 waves split rows)
__global__ void col_kernel(const float* __restrict__ K, const float* __restrict__ u,
                           float* __restrict__ v) {
  __shared__ float red[4][64];
  int t = threadIdx.x;
  int b = blockIdx.x >> 3, jb = (blockIdx.x & 7) * 64;
  int lane = t & 63, w = t >> 6;
  const float* ub = u + b * 512;
  float acc = 0.f;
  for (int i = w; i < 512; i += 4)
    acc += K[(size_t)(b * 512 + i) * 512 + jb + lane] * ub[i];
  red[w][lane] = acc;
  __syncthreads();
  if (t < 64) {
    float tot = red[0][t] + red[1][t] + red[2][t] + red[3][t];
    v[b * 512 + jb + t] = INVN / tot;
  }
}

// P = u[i] * K * v[j] in place
__global__ void pout_kernel(float* __restrict__ K, const float* __restrict__ u,
                            const float* __restrict__ v) {
  int i = blockIdx.x * 256 + threadIdx.x;   // f4 index
  int batch = i >> 16;
  int rem = i & 65535;
  int row = rem >> 7;
  int c4 = rem & 127;
  float uu = u[batch * 512 + row];
  float4 v4 = ((const float4*)(v + batch * 512))[c4];
  float4 k = ((float4*)K)[i];
  k.x *= uu * v4.x; k.y *= uu * v4.y;
  k.z *= uu * v4.z; k.w *= uu * v4.w;
  ((float4*)K)[i] = k;
}

extern "C" void kernel_launch(void* const* d_in, const int* in_sizes, int n_in,
                              void* d_out, int out_size, void* d_ws, size_t ws_size,
                              hipStream_t stream) {
  const float* emb_in  = (const float*)d_in[0];
  const void*  maskp   = d_in[1];
  const float* emb_out = (const float*)d_in[2];
  const float* pad     = (const float*)d_in[3];
  const float* pos     = (const float*)d_in[4];
  const float* Win     = (const float*)d_in[5];
  const float* bin     = (const float*)d_in[6];
  const float* Wout    = (const float*)d_in[7];
  const float* bout    = (const float*)d_in[8];
  float* C = (float*)d_out;                 // C -> K -> P, all in place (8 MB)
  char* ws = (char*)d_ws;
  int*   det   = (int*)ws;
  float* invES = (float*)(ws + 256);
  float* u     = (float*)(ws + 4096);
  float* v     = (float*)(ws + 20480);
  float* bsum  = (float*)(ws + 36864);
  float* a     = (float*)(ws + 69632);
  float* bv    = (float*)(ws + 593920);

  detect_mask_kernel<<<1, 256, 0, stream>>>((const unsigned char*)maskp, det);
  embed_gemm_kernel<<<512, 256, 0, stream>>>(emb_in, maskp, emb_out, pad, pos,
                                             Win, bin, Wout, bout, det, a, bv);
  cost_kernel<<<8192, 256, 0, stream>>>(a, bv, C, bsum);
  norm_kernel<<<8, 256, 0, stream>>>(bsum, invES);
  expk_kernel<<<2048, 256, 0, stream>>>(C, invES);

  row_kernel<<<1024, 256, 0, stream>>>(C, v, u, 0);   // v implicit = 1
  col_kernel<<<64, 256, 0, stream>>>(C, u, v);
  for (int it = 1; it < ITERS; ++it) {
    row_kernel<<<1024, 256, 0, stream>>>(C, v, u, 1);
    col_kernel<<<64, 256, 0, stream>>>(C, u, v);
  }
  pout_kernel<<<2048, 256, 0, stream>>>(C, u, v);
}